// Round 1
// baseline (284.409 us; speedup 1.0000x reference)
//
#include <hip/hip_runtime.h>
#include <hip/hip_bf16.h>

#define T_TOK 2048
#define H_DIM 1024
#define I_DIM 768
#define NEXP  8

typedef short bf16x8  __attribute__((ext_vector_type(8)));
typedef short short4v __attribute__((ext_vector_type(4)));
typedef float f32x4   __attribute__((ext_vector_type(4)));

constexpr int BM = 128, BN = 128, BK = 32, LDK = 40;  // LDK pad: 32->40 shorts (80B rows, 2-way LDS alias only)
constexpr int MT_MAX = T_TOK / BM;   // 16 worst-case m-tiles per expert
constexpr int NT1 = I_DIM / BN;      // 6
constexpr int NT2 = H_DIM / BN;      // 8

__device__ __forceinline__ short f2bf(float f) {
  __bf16 b = (__bf16)f;              // RNE; compiler packs pairs into v_cvt_pk_bf16_f32
  return __builtin_bit_cast(short, b);
}

// ---- Phase 0: deterministic routing compaction. 1 block, 8 waves, wave e owns expert e.
__global__ void moe_compact(const float* __restrict__ routw,
                            int* __restrict__ lists, int* __restrict__ counts) {
  int lane = threadIdx.x & 63;
  int e    = threadIdx.x >> 6;
  int base = 0;
  for (int t0 = 0; t0 < T_TOK; t0 += 64) {
    float w = routw[(size_t)(t0 + lane) * NEXP + e];
    unsigned long long mask = __ballot(w > 0.0f);
    if (w > 0.0f) {
      int pos = __popcll(mask & ((1ull << lane) - 1));
      lists[e * T_TOK + base + pos] = t0 + lane;
    }
    base += __popcll(mask);
  }
  if (lane == 0) counts[e] = base;
}

// ---- Phase 1: per-expert gathered GEMM  h = silu(X Wg^T) * (X Wu^T), bf16 out.
__global__ __launch_bounds__(256, 2) void moe_gemm1(
    const float* __restrict__ x, const float* __restrict__ gate_w,
    const float* __restrict__ up_w, const int* __restrict__ lists,
    const int* __restrict__ counts, unsigned short* __restrict__ h_ws) {
  int bid = blockIdx.x;
  int e  = bid / (NT1 * MT_MAX);
  int r2 = bid % (NT1 * MT_MAX);
  int nt = r2 / MT_MAX;
  int mt = r2 % MT_MAX;
  int cnt = counts[e];
  int m0 = mt * BM;
  if (m0 >= cnt) return;
  int n0 = nt * BN;

  __shared__ short lA[BM * LDK];
  __shared__ short lG[BN * LDK];
  __shared__ short lU[BN * LDK];

  int tid = threadIdx.x;
  int lane = tid & 63, wid = tid >> 6;
  int wm = wid >> 1, wn = wid & 1;
  int fr = lane & 15, fg = lane >> 4;

  int sr = tid >> 3;          // staging row 0..31 (x4 passes)
  int sc = (tid & 7) * 4;     // staging float col

  int tok[4];
#pragma unroll
  for (int p = 0; p < 4; ++p) {
    int r = p * 32 + sr;
    tok[p] = (m0 + r < cnt) ? lists[e * T_TOK + m0 + r] : -1;
  }
  const float* gw = gate_w + ((size_t)e * I_DIM + n0) * H_DIM;
  const float* uw = up_w   + ((size_t)e * I_DIM + n0) * H_DIM;

  f32x4 accG[4][4] = {};
  f32x4 accU[4][4] = {};

  for (int k0 = 0; k0 < H_DIM; k0 += BK) {
#pragma unroll
    for (int p = 0; p < 4; ++p) {
      int r = p * 32 + sr;
      float4 va = make_float4(0.f, 0.f, 0.f, 0.f);
      if (tok[p] >= 0) va = *(const float4*)(x + (size_t)tok[p] * H_DIM + k0 + sc);
      float4 vg = *(const float4*)(gw + (size_t)r * H_DIM + k0 + sc);
      float4 vu = *(const float4*)(uw + (size_t)r * H_DIM + k0 + sc);
      short4v a4 = {f2bf(va.x), f2bf(va.y), f2bf(va.z), f2bf(va.w)};
      short4v g4 = {f2bf(vg.x), f2bf(vg.y), f2bf(vg.z), f2bf(vg.w)};
      short4v u4 = {f2bf(vu.x), f2bf(vu.y), f2bf(vu.z), f2bf(vu.w)};
      *(short4v*)(lA + r * LDK + sc) = a4;
      *(short4v*)(lG + r * LDK + sc) = g4;
      *(short4v*)(lU + r * LDK + sc) = u4;
    }
    __syncthreads();
    bf16x8 af[4], gf[4], uf[4];
#pragma unroll
    for (int m = 0; m < 4; ++m)
      af[m] = *(const bf16x8*)(lA + (wm * 64 + m * 16 + fr) * LDK + fg * 8);
#pragma unroll
    for (int n = 0; n < 4; ++n) {
      gf[n] = *(const bf16x8*)(lG + (wn * 64 + n * 16 + fr) * LDK + fg * 8);
      uf[n] = *(const bf16x8*)(lU + (wn * 64 + n * 16 + fr) * LDK + fg * 8);
    }
#pragma unroll
    for (int m = 0; m < 4; ++m)
#pragma unroll
      for (int n = 0; n < 4; ++n) {
        accG[m][n] = __builtin_amdgcn_mfma_f32_16x16x32_bf16(af[m], gf[n], accG[m][n], 0, 0, 0);
        accU[m][n] = __builtin_amdgcn_mfma_f32_16x16x32_bf16(af[m], uf[n], accU[m][n], 0, 0, 0);
      }
    __syncthreads();
  }

#pragma unroll
  for (int m = 0; m < 4; ++m) {
#pragma unroll
    for (int j = 0; j < 4; ++j) {
      int lr = wm * 64 + m * 16 + fg * 4 + j;  // C/D: col=lane&15, row=(lane>>4)*4+reg (m89/m91)
      int grow = m0 + lr;
      if (grow < cnt) {
        size_t rowbase = (size_t)(e * T_TOK + grow) * I_DIM + n0 + wn * 64;
#pragma unroll
        for (int n = 0; n < 4; ++n) {
          float g = accG[m][n][j];
          float u = accU[m][n][j];
          float h = g * u / (1.f + __expf(-g));   // silu(g)*u
          h_ws[rowbase + n * 16 + fr] = (unsigned short)f2bf(h);
        }
      }
    }
  }
}

// ---- Phase 2: per-expert GEMM  out[t] += route_w * (h_e down_w[e]^T)
__global__ __launch_bounds__(256, 2) void moe_gemm2(
    const unsigned short* __restrict__ h_ws, const float* __restrict__ down_w,
    const int* __restrict__ lists, const int* __restrict__ counts,
    const float* __restrict__ routw, float* __restrict__ out) {
  int bid = blockIdx.x;
  int e  = bid / (NT2 * MT_MAX);
  int r2 = bid % (NT2 * MT_MAX);
  int nt = r2 / MT_MAX;
  int mt = r2 % MT_MAX;
  int cnt = counts[e];
  int m0 = mt * BM;
  if (m0 >= cnt) return;
  int n0 = nt * BN;

  __shared__ short lA[BM * LDK];
  __shared__ short lB[BN * LDK];

  int tid = threadIdx.x;
  int lane = tid & 63, wid = tid >> 6;
  int wm = wid >> 1, wn = wid & 1;
  int fr = lane & 15, fg = lane >> 4;

  int ar = tid >> 2;          // A staging: 4 lanes/row of 8 bf16, rows 0..63 (x2)
  int ac = (tid & 3) * 8;
  int br = tid >> 3;          // B staging: 8 lanes/row of 4 f32, rows 0..31 (x4)
  int bc = (tid & 7) * 4;

  const float* dw = down_w + ((size_t)e * H_DIM + n0) * I_DIM;

  f32x4 acc[4][4] = {};

  for (int k0 = 0; k0 < I_DIM; k0 += BK) {
#pragma unroll
    for (int p = 0; p < 2; ++p) {
      int r = p * 64 + ar;
      bf16x8 v = {0, 0, 0, 0, 0, 0, 0, 0};
      if (m0 + r < cnt)
        v = *(const bf16x8*)(h_ws + (size_t)(e * T_TOK + m0 + r) * I_DIM + k0 + ac);
      *(bf16x8*)(lA + r * LDK + ac) = v;
    }
#pragma unroll
    for (int p = 0; p < 4; ++p) {
      int r = p * 32 + br;
      float4 vb = *(const float4*)(dw + (size_t)r * I_DIM + k0 + bc);
      short4v b4 = {f2bf(vb.x), f2bf(vb.y), f2bf(vb.z), f2bf(vb.w)};
      *(short4v*)(lB + r * LDK + bc) = b4;
    }
    __syncthreads();
    bf16x8 af[4], bfr[4];
#pragma unroll
    for (int m = 0; m < 4; ++m)
      af[m] = *(const bf16x8*)(lA + (wm * 64 + m * 16 + fr) * LDK + fg * 8);
#pragma unroll
    for (int n = 0; n < 4; ++n)
      bfr[n] = *(const bf16x8*)(lB + (wn * 64 + n * 16 + fr) * LDK + fg * 8);
#pragma unroll
    for (int m = 0; m < 4; ++m)
#pragma unroll
      for (int n = 0; n < 4; ++n)
        acc[m][n] = __builtin_amdgcn_mfma_f32_16x16x32_bf16(af[m], bfr[n], acc[m][n], 0, 0, 0);
    __syncthreads();
  }

#pragma unroll
  for (int m = 0; m < 4; ++m) {
#pragma unroll
    for (int j = 0; j < 4; ++j) {
      int lr = wm * 64 + m * 16 + fg * 4 + j;
      int grow = m0 + lr;
      if (grow < cnt) {
        int t = lists[e * T_TOK + grow];
        float w = routw[(size_t)t * NEXP + e];
        float* orow = out + (size_t)t * H_DIM + n0 + wn * 64;
#pragma unroll
        for (int n = 0; n < 4; ++n)
          atomicAdd(orow + n * 16 + fr, acc[m][n][j] * w);
      }
    }
  }
}

extern "C" void kernel_launch(void* const* d_in, const int* in_sizes, int n_in,
                              void* d_out, int out_size, void* d_ws, size_t ws_size,
                              hipStream_t stream) {
  const float* x      = (const float*)d_in[0];
  const float* gate_w = (const float*)d_in[1];
  const float* up_w   = (const float*)d_in[2];
  const float* down_w = (const float*)d_in[3];
  const float* routw  = (const float*)d_in[4];
  // d_in[5] expert_select_count unused (we recompute counts deterministically)
  float* out = (float*)d_out;

  // ws layout: [0,32) counts; [256, 256+64K) lists; [128K, 128K+25.2MB) h_ws (bf16)
  int* counts = (int*)d_ws;
  int* lists  = (int*)((char*)d_ws + 256);
  unsigned short* h_ws = (unsigned short*)((char*)d_ws + (1 << 17));

  hipMemsetAsync(d_out, 0, (size_t)out_size * sizeof(float), stream);
  moe_compact<<<1, 512, 0, stream>>>(routw, lists, counts);
  moe_gemm1<<<NEXP * NT1 * MT_MAX, 256, 0, stream>>>(x, gate_w, up_w, lists, counts, h_ws);
  moe_gemm2<<<NEXP * NT2 * MT_MAX, 256, 0, stream>>>(h_ws, down_w, lists, counts, routw, out);
}

// Round 2
// 193.349 us; speedup vs baseline: 1.4710x; 1.4710x over previous
//
#include <hip/hip_runtime.h>
#include <hip/hip_bf16.h>

#define T_TOK 2048
#define H_DIM 1024
#define I_DIM 768
#define NEXP  8

typedef short bf16x8  __attribute__((ext_vector_type(8)));
typedef short short4v __attribute__((ext_vector_type(4)));
typedef float f32x4   __attribute__((ext_vector_type(4)));

constexpr int BM = 128, BN = 128, BK = 32, LDK = 40;  // LDK pad: 80B rows -> 2-way LDS alias only (free, m136)
constexpr int MT_MAX = T_TOK / BM;   // 16 worst-case m-tiles per expert
constexpr int NT1 = I_DIM / BN;      // 6
constexpr int NT2 = H_DIM / BN;      // 8

__device__ __forceinline__ short f2bf(float f) {
  __bf16 b = (__bf16)f;              // RNE; pairs pack into v_cvt_pk_bf16_f32
  return __builtin_bit_cast(short, b);
}

// ---- Phase 0: deterministic routing compaction. 1 block, 8 waves, wave e owns expert e.
__global__ void moe_compact(const float* __restrict__ routw,
                            int* __restrict__ lists, int* __restrict__ counts) {
  int lane = threadIdx.x & 63;
  int e    = threadIdx.x >> 6;
  int base = 0;
  for (int t0 = 0; t0 < T_TOK; t0 += 64) {
    float w = routw[(size_t)(t0 + lane) * NEXP + e];
    unsigned long long mask = __ballot(w > 0.0f);
    if (w > 0.0f) {
      int pos = __popcll(mask & ((1ull << lane) - 1));
      lists[e * T_TOK + base + pos] = t0 + lane;
    }
    base += __popcll(mask);
  }
  if (lane == 0) counts[e] = base;
}

// ---- Phase 1: per-expert gathered GEMM  h = silu(X Wg^T) * (X Wu^T), bf16 out.
// 512 threads / 8 waves; per-wave 32x64 output; acc = 16 f32x4 (same reg profile as gemm2).
__global__ __launch_bounds__(512, 2) void moe_gemm1(
    const float* __restrict__ x, const float* __restrict__ gate_w,
    const float* __restrict__ up_w, const int* __restrict__ lists,
    const int* __restrict__ counts, unsigned short* __restrict__ h_ws) {
  int bid = blockIdx.x;
  int e  = bid / (NT1 * MT_MAX);
  int r2 = bid % (NT1 * MT_MAX);
  int nt = r2 / MT_MAX;
  int mt = r2 % MT_MAX;
  int cnt = counts[e];
  int m0 = mt * BM;
  if (m0 >= cnt) return;
  int n0 = nt * BN;

  __shared__ short lA[BM * LDK];
  __shared__ short lG[BN * LDK];
  __shared__ short lU[BN * LDK];

  int tid = threadIdx.x;
  int lane = tid & 63, wid = tid >> 6;   // wid 0..7
  int wm = wid >> 1, wn = wid & 1;       // wave grid 4x2 over 128x128 -> 32x64 per wave
  int fr = lane & 15, fg = lane >> 4;

  int sr = tid >> 3;          // staging row 0..63 (x2 passes)
  int sc = (tid & 7) * 4;     // staging float col

  int tok[2];
#pragma unroll
  for (int p = 0; p < 2; ++p) {
    int r = p * 64 + sr;
    tok[p] = (m0 + r < cnt) ? lists[e * T_TOK + m0 + r] : -1;
  }
  const float* gw = gate_w + ((size_t)e * I_DIM + n0) * H_DIM;
  const float* uw = up_w   + ((size_t)e * I_DIM + n0) * H_DIM;

  f32x4 accG[2][4] = {};
  f32x4 accU[2][4] = {};

  for (int k0 = 0; k0 < H_DIM; k0 += BK) {
    // batched register staging: issue ALL global loads, then convert+write
    float4 va[2], vg[2], vu[2];
#pragma unroll
    for (int p = 0; p < 2; ++p) {
      int r = p * 64 + sr;
      va[p] = (tok[p] >= 0) ? *(const float4*)(x + (size_t)tok[p] * H_DIM + k0 + sc)
                            : make_float4(0.f, 0.f, 0.f, 0.f);
      vg[p] = *(const float4*)(gw + (size_t)r * H_DIM + k0 + sc);
      vu[p] = *(const float4*)(uw + (size_t)r * H_DIM + k0 + sc);
    }
#pragma unroll
    for (int p = 0; p < 2; ++p) {
      int r = p * 64 + sr;
      short4v a4 = {f2bf(va[p].x), f2bf(va[p].y), f2bf(va[p].z), f2bf(va[p].w)};
      short4v g4 = {f2bf(vg[p].x), f2bf(vg[p].y), f2bf(vg[p].z), f2bf(vg[p].w)};
      short4v u4 = {f2bf(vu[p].x), f2bf(vu[p].y), f2bf(vu[p].z), f2bf(vu[p].w)};
      *(short4v*)(lA + r * LDK + sc) = a4;
      *(short4v*)(lG + r * LDK + sc) = g4;
      *(short4v*)(lU + r * LDK + sc) = u4;
    }
    __syncthreads();
    bf16x8 af[2], gf[4], uf[4];
#pragma unroll
    for (int m = 0; m < 2; ++m)
      af[m] = *(const bf16x8*)(lA + (wm * 32 + m * 16 + fr) * LDK + fg * 8);
#pragma unroll
    for (int n = 0; n < 4; ++n) {
      gf[n] = *(const bf16x8*)(lG + (wn * 64 + n * 16 + fr) * LDK + fg * 8);
      uf[n] = *(const bf16x8*)(lU + (wn * 64 + n * 16 + fr) * LDK + fg * 8);
    }
#pragma unroll
    for (int m = 0; m < 2; ++m)
#pragma unroll
      for (int n = 0; n < 4; ++n) {
        accG[m][n] = __builtin_amdgcn_mfma_f32_16x16x32_bf16(af[m], gf[n], accG[m][n], 0, 0, 0);
        accU[m][n] = __builtin_amdgcn_mfma_f32_16x16x32_bf16(af[m], uf[n], accU[m][n], 0, 0, 0);
      }
    __syncthreads();
  }

#pragma unroll
  for (int m = 0; m < 2; ++m) {
#pragma unroll
    for (int j = 0; j < 4; ++j) {
      int lr = wm * 32 + m * 16 + fg * 4 + j;  // C/D: col=lane&15, row=(lane>>4)*4+reg (m89/m91)
      int grow = m0 + lr;
      if (grow < cnt) {
        size_t rowbase = (size_t)(e * T_TOK + grow) * I_DIM + n0 + wn * 64;
#pragma unroll
        for (int n = 0; n < 4; ++n) {
          float g = accG[m][n][j];
          float u = accU[m][n][j];
          float h = g * u / (1.f + __expf(-g));   // silu(g)*u
          h_ws[rowbase + n * 16 + fr] = (unsigned short)f2bf(h);
        }
      }
    }
  }
}

// ---- Phase 2: per-expert GEMM  out[t] += route_w * (h_e down_w[e]^T)
__global__ __launch_bounds__(256, 2) void moe_gemm2(
    const unsigned short* __restrict__ h_ws, const float* __restrict__ down_w,
    const int* __restrict__ lists, const int* __restrict__ counts,
    const float* __restrict__ routw, float* __restrict__ out) {
  int bid = blockIdx.x;
  int e  = bid / (NT2 * MT_MAX);
  int r2 = bid % (NT2 * MT_MAX);
  int nt = r2 / MT_MAX;
  int mt = r2 % MT_MAX;
  int cnt = counts[e];
  int m0 = mt * BM;
  if (m0 >= cnt) return;
  int n0 = nt * BN;

  __shared__ short lA[BM * LDK];
  __shared__ short lB[BN * LDK];

  int tid = threadIdx.x;
  int lane = tid & 63, wid = tid >> 6;
  int wm = wid >> 1, wn = wid & 1;
  int fr = lane & 15, fg = lane >> 4;

  int ar = tid >> 2;          // A staging: 4 lanes/row of 8 bf16, rows 0..63 (x2)
  int ac = (tid & 3) * 8;
  int br = tid >> 3;          // B staging: 8 lanes/row of 4 f32, rows 0..31 (x4)
  int bc = (tid & 7) * 4;

  const float* dw = down_w + ((size_t)e * H_DIM + n0) * I_DIM;

  f32x4 acc[4][4] = {};

  for (int k0 = 0; k0 < I_DIM; k0 += BK) {
    // batched register staging
    bf16x8 va[2];
    float4 vb[4];
#pragma unroll
    for (int p = 0; p < 2; ++p) {
      int r = p * 64 + ar;
      bf16x8 v = {0, 0, 0, 0, 0, 0, 0, 0};
      if (m0 + r < cnt)
        v = *(const bf16x8*)(h_ws + (size_t)(e * T_TOK + m0 + r) * I_DIM + k0 + ac);
      va[p] = v;
    }
#pragma unroll
    for (int p = 0; p < 4; ++p) {
      int r = p * 32 + br;
      vb[p] = *(const float4*)(dw + (size_t)r * I_DIM + k0 + bc);
    }
#pragma unroll
    for (int p = 0; p < 2; ++p)
      *(bf16x8*)(lA + (p * 64 + ar) * LDK + ac) = va[p];
#pragma unroll
    for (int p = 0; p < 4; ++p) {
      short4v b4 = {f2bf(vb[p].x), f2bf(vb[p].y), f2bf(vb[p].z), f2bf(vb[p].w)};
      *(short4v*)(lB + (p * 32 + br) * LDK + bc) = b4;
    }
    __syncthreads();
    bf16x8 af[4], bfr[4];
#pragma unroll
    for (int m = 0; m < 4; ++m)
      af[m] = *(const bf16x8*)(lA + (wm * 64 + m * 16 + fr) * LDK + fg * 8);
#pragma unroll
    for (int n = 0; n < 4; ++n)
      bfr[n] = *(const bf16x8*)(lB + (wn * 64 + n * 16 + fr) * LDK + fg * 8);
#pragma unroll
    for (int m = 0; m < 4; ++m)
#pragma unroll
      for (int n = 0; n < 4; ++n)
        acc[m][n] = __builtin_amdgcn_mfma_f32_16x16x32_bf16(af[m], bfr[n], acc[m][n], 0, 0, 0);
    __syncthreads();
  }

#pragma unroll
  for (int m = 0; m < 4; ++m) {
#pragma unroll
    for (int j = 0; j < 4; ++j) {
      int lr = wm * 64 + m * 16 + fg * 4 + j;
      int grow = m0 + lr;
      if (grow < cnt) {
        int t = lists[e * T_TOK + grow];
        float w = routw[(size_t)t * NEXP + e];
        float* orow = out + (size_t)t * H_DIM + n0 + wn * 64;
#pragma unroll
        for (int n = 0; n < 4; ++n)
          atomicAdd(orow + n * 16 + fr, acc[m][n][j] * w);
      }
    }
  }
}

extern "C" void kernel_launch(void* const* d_in, const int* in_sizes, int n_in,
                              void* d_out, int out_size, void* d_ws, size_t ws_size,
                              hipStream_t stream) {
  const float* x      = (const float*)d_in[0];
  const float* gate_w = (const float*)d_in[1];
  const float* up_w   = (const float*)d_in[2];
  const float* down_w = (const float*)d_in[3];
  const float* routw  = (const float*)d_in[4];
  float* out = (float*)d_out;

  // ws layout: [0,32) counts; [256, 256+64K) lists; [128K, 128K+25.2MB) h_ws (bf16)
  int* counts = (int*)d_ws;
  int* lists  = (int*)((char*)d_ws + 256);
  unsigned short* h_ws = (unsigned short*)((char*)d_ws + (1 << 17));

  hipMemsetAsync(d_out, 0, (size_t)out_size * sizeof(float), stream);
  moe_compact<<<1, 512, 0, stream>>>(routw, lists, counts);
  moe_gemm1<<<NEXP * NT1 * MT_MAX, 512, 0, stream>>>(x, gate_w, up_w, lists, counts, h_ws);
  moe_gemm2<<<NEXP * NT2 * MT_MAX, 256, 0, stream>>>(h_ws, down_w, lists, counts, routw, out);
}

// Round 3
// 129.027 us; speedup vs baseline: 2.2043x; 1.4985x over previous
//
#include <hip/hip_runtime.h>
#include <hip/hip_bf16.h>

#define T_TOK 2048
#define H_DIM 1024
#define I_DIM 768
#define NEXP  8

typedef short bf16x8  __attribute__((ext_vector_type(8)));
typedef short short4v __attribute__((ext_vector_type(4)));
typedef float f32x4   __attribute__((ext_vector_type(4)));

__device__ __forceinline__ short f2bf(float f) {
  __bf16 b = (__bf16)f;              // RNE; pairs pack into v_cvt_pk_bf16_f32
  return __builtin_bit_cast(short, b);
}

__device__ __forceinline__ void gload16(const void* g, void* l) {
  __builtin_amdgcn_global_load_lds(
      (const __attribute__((address_space(1))) void*)g,
      (__attribute__((address_space(3))) void*)l, 16, 0, 0);
}

// ---------------- ws layout (Path A), bytes ----------------
// 0: counts[8] | 64: pads[8] | 128: bases[8] | 256: lists[8*2048]
// 131072: wbf = gate_bf(6291456) ++ up_bf(6291456) ++ down_bf(6291456) shorts
// 37879808: xc (5120*1024 shorts) | 48365568: h (5120*768 shorts) | end 56229888
#define WS_A_BYTES 56229888ULL
#define WPE 6291456   // weight elems per array

// ---- shared: routing compaction + prefix bases (1 block, 8 waves)
__global__ void moe_compact(const float* __restrict__ routw, int* __restrict__ wsI) {
  int lane = threadIdx.x & 63;
  int e    = threadIdx.x >> 6;
  int base = 0;
  for (int t0 = 0; t0 < T_TOK; t0 += 64) {
    float w = routw[(size_t)(t0 + lane) * NEXP + e];
    unsigned long long mask = __ballot(w > 0.0f);
    if (w > 0.0f) {
      int pos = __popcll(mask & ((1ull << lane) - 1));
      wsI[64 + e * T_TOK + base + pos] = t0 + lane;
    }
    base += __popcll(mask);
  }
  if (lane == 0) wsI[e] = base;
  __syncthreads();
  if (threadIdx.x == 0) {
    int acc = 0;
    for (int i = 0; i < NEXP; ++i) {
      int c = wsI[i];
      int p = (c + 127) & ~127;
      wsI[16 + i] = p;      // pads
      wsI[32 + i] = acc;    // bases
      acc += p;
    }
  }
}

// ---- Path A: weight fp32->bf16 convert (grid 2304 x 512, exact cover)
__global__ __launch_bounds__(512) void wconv(const float* __restrict__ g,
                                             const float* __restrict__ u,
                                             const float* __restrict__ d,
                                             unsigned short* __restrict__ wbf) {
  int gid = blockIdx.x * 512 + threadIdx.x;   // 1179648 groups of 16 elems
  int a = gid / 393216;                       // 0:gate 1:up 2:down
  int rem = (gid - a * 393216) * 16;
  const float* s = (a == 0) ? g : (a == 1) ? u : d;
  unsigned short* o = wbf + (size_t)a * WPE + rem;
#pragma unroll
  for (int j = 0; j < 4; ++j) {
    float4 v = *(const float4*)(s + rem + j * 4);
    short4v b = {f2bf(v.x), f2bf(v.y), f2bf(v.z), f2bf(v.w)};
    *(short4v*)(o + j * 4) = b;
  }
}

// ---- Path A: gather+convert x rows into compacted bf16 (zero-pad to pads[e])
__global__ __launch_bounds__(256) void xgather(const float* __restrict__ x,
                                               const int* __restrict__ wsI,
                                               unsigned short* __restrict__ xc) {
  int e = blockIdx.x >> 5, c = blockIdx.x & 31;
  int cnt = wsI[e], pad = wsI[16 + e], base = wsI[32 + e];
  int r0 = c * 64;
  if (r0 >= pad) return;
  int t = threadIdx.x;
  int r1 = min(r0 + 64, pad);
  for (int r = r0; r < r1; ++r) {
    unsigned short* dst = xc + (size_t)(base + r) * H_DIM + t * 4;
    if (r < cnt) {
      int tok = wsI[64 + e * T_TOK + r];
      float4 v = *(const float4*)(x + (size_t)tok * H_DIM + t * 4);
      short4v b = {f2bf(v.x), f2bf(v.y), f2bf(v.z), f2bf(v.w)};
      *(short4v*)dst = b;
    } else {
      short4v z = {0, 0, 0, 0};
      *(short4v*)dst = z;
    }
  }
}

// ---- Path A gemm1: h = silu(Xc Wg^T)*(Xc Wu^T). 128x64 tile, BK=32, gload_lds dbuf.
// grid = 8e * 16mt * 12nt = 1536 (e = bid&7 -> XCD pinning), 512 thr / 8 waves.
__global__ __launch_bounds__(512, 4) void moe_gemm1a(
    const unsigned short* __restrict__ xc, const unsigned short* __restrict__ wbf,
    const int* __restrict__ wsI, unsigned short* __restrict__ h) {
  int e = blockIdx.x & 7, r = blockIdx.x >> 3;
  int mt = r & 15, nt = r >> 4;              // nt 0..11
  int cnt = wsI[e];
  int m0 = mt * 128;
  if (m0 >= cnt) return;
  int base = wsI[32 + e];
  int n0 = nt * 64;
  const unsigned short* gate_bf = wbf;
  const unsigned short* up_bf   = wbf + WPE;

  __shared__ unsigned short ls[2][8192];     // A[128][32] @0, G[64][32] @4096, U[64][32] @6144

  int tid = threadIdx.x, lane = tid & 63, wid = tid >> 6;
  int wm = wid >> 1, wn = wid & 1;           // wave grid 4(M)x2(N): 32x32 per wave
  int fr = lane & 15, fg = lane >> 4;

  int srow = lane >> 2;                      // 0..15 within chunk
  int scol = (lane & 3) * 8;                 // elem col within BK
  const unsigned short* srcA = xc + (size_t)(base + m0 + wid * 16 + srow) * H_DIM + scol;
  const unsigned short* srcW = ((wid < 4) ? gate_bf : up_bf)
      + (size_t)(e * I_DIM + n0 + (wid & 3) * 16 + srow) * H_DIM + scol;
  int ldsA = wid * 512;                                   // shorts
  int ldsW = (wid < 4) ? (4096 + wid * 512) : (6144 + (wid - 4) * 512);

  f32x4 accG[2][2] = {};
  f32x4 accU[2][2] = {};

  // prologue: stage K-step 0 into buf 0
  gload16(srcA, &ls[0][ldsA]);
  gload16(srcW, &ls[0][ldsW]);
  __syncthreads();

  for (int k = 0; k < H_DIM / 32; ++k) {
    int cur = k & 1;
    if (k + 1 < H_DIM / 32) {
      gload16(srcA + (k + 1) * 32, &ls[cur ^ 1][ldsA]);
      gload16(srcW + (k + 1) * 32, &ls[cur ^ 1][ldsW]);
    }
    bf16x8 af[2], gf[2], uf[2];
#pragma unroll
    for (int m = 0; m < 2; ++m)
      af[m] = *(const bf16x8*)&ls[cur][(wm * 32 + m * 16 + fr) * 32 + fg * 8];
#pragma unroll
    for (int n = 0; n < 2; ++n) {
      gf[n] = *(const bf16x8*)&ls[cur][4096 + (wn * 32 + n * 16 + fr) * 32 + fg * 8];
      uf[n] = *(const bf16x8*)&ls[cur][6144 + (wn * 32 + n * 16 + fr) * 32 + fg * 8];
    }
#pragma unroll
    for (int m = 0; m < 2; ++m)
#pragma unroll
      for (int n = 0; n < 2; ++n) {
        accG[m][n] = __builtin_amdgcn_mfma_f32_16x16x32_bf16(af[m], gf[n], accG[m][n], 0, 0, 0);
        accU[m][n] = __builtin_amdgcn_mfma_f32_16x16x32_bf16(af[m], uf[n], accU[m][n], 0, 0, 0);
      }
    __syncthreads();   // drains stage loads (vmcnt0) + LDS reads before overwrite
  }

#pragma unroll
  for (int m = 0; m < 2; ++m)
#pragma unroll
    for (int j = 0; j < 4; ++j) {
      int lr = wm * 32 + m * 16 + fg * 4 + j;   // C/D: col=lane&15, row=(lane>>4)*4+reg
      size_t rowbase = (size_t)(base + m0 + lr) * I_DIM + n0 + wn * 32;
#pragma unroll
      for (int n = 0; n < 2; ++n) {
        float g = accG[m][n][j];
        float u = accU[m][n][j];
        float hv = g * u / (1.f + __expf(-g));
        h[rowbase + n * 16 + fr] = (unsigned short)f2bf(hv);   // rows>=cnt are exact zeros
      }
    }
}

// ---- Path A gemm2: out[t] += w * (h_e down^T). 128x128 tile, BK=32, gload_lds dbuf.
// grid = 8e * 16mt * 8nt = 1024, 512 thr / 8 waves.
__global__ __launch_bounds__(512, 4) void moe_gemm2a(
    const unsigned short* __restrict__ h, const unsigned short* __restrict__ wbf,
    const int* __restrict__ wsI, const float* __restrict__ routw,
    float* __restrict__ out) {
  int e = blockIdx.x & 7, r = blockIdx.x >> 3;
  int mt = r & 15, nt = r >> 4;              // nt 0..7
  int cnt = wsI[e];
  int m0 = mt * 128;
  if (m0 >= cnt) return;
  int base = wsI[32 + e];
  int n0 = nt * 128;
  const unsigned short* down_bf = wbf + 2 * WPE;

  __shared__ unsigned short ls[2][8192];     // A[128][32] @0, B[128][32] @4096

  int tid = threadIdx.x, lane = tid & 63, wid = tid >> 6;
  int wm = wid >> 1, wn = wid & 1;           // wave 32(M) x 64(N)
  int fr = lane & 15, fg = lane >> 4;

  int srow = lane >> 2;
  int scol = (lane & 3) * 8;
  const unsigned short* srcA = h + (size_t)(base + m0 + wid * 16 + srow) * I_DIM + scol;
  const unsigned short* srcB = down_bf + (size_t)(e * H_DIM + n0 + wid * 16 + srow) * I_DIM + scol;
  int ldsA = wid * 512;
  int ldsB = 4096 + wid * 512;

  f32x4 acc[2][4] = {};

  gload16(srcA, &ls[0][ldsA]);
  gload16(srcB, &ls[0][ldsB]);
  __syncthreads();

  for (int k = 0; k < I_DIM / 32; ++k) {
    int cur = k & 1;
    if (k + 1 < I_DIM / 32) {
      gload16(srcA + (k + 1) * 32, &ls[cur ^ 1][ldsA]);
      gload16(srcB + (k + 1) * 32, &ls[cur ^ 1][ldsB]);
    }
    bf16x8 af[2], bf[4];
#pragma unroll
    for (int m = 0; m < 2; ++m)
      af[m] = *(const bf16x8*)&ls[cur][(wm * 32 + m * 16 + fr) * 32 + fg * 8];
#pragma unroll
    for (int n = 0; n < 4; ++n)
      bf[n] = *(const bf16x8*)&ls[cur][4096 + (wn * 64 + n * 16 + fr) * 32 + fg * 8];
#pragma unroll
    for (int m = 0; m < 2; ++m)
#pragma unroll
      for (int n = 0; n < 4; ++n)
        acc[m][n] = __builtin_amdgcn_mfma_f32_16x16x32_bf16(af[m], bf[n], acc[m][n], 0, 0, 0);
    __syncthreads();
  }

#pragma unroll
  for (int m = 0; m < 2; ++m)
#pragma unroll
    for (int j = 0; j < 4; ++j) {
      int lr = wm * 32 + m * 16 + fg * 4 + j;
      int grow = m0 + lr;
      if (grow < cnt) {
        int t = wsI[64 + e * T_TOK + grow];
        float w = routw[(size_t)t * NEXP + e];
        float* orow = out + (size_t)t * H_DIM + n0 + wn * 64;
#pragma unroll
        for (int n = 0; n < 4; ++n)
          atomicAdd(orow + n * 16 + fr, acc[m][n][j] * w);
      }
    }
}

// ================= Path B fallback (round-2 kernels, ws-frugal) =================
constexpr int BMf = 128, BNf = 128, LDKf = 40;
constexpr int MT_MAX = T_TOK / 128;
constexpr int NT1f = I_DIM / BNf;   // 6
constexpr int NT2f = H_DIM / BNf;   // 8

__global__ __launch_bounds__(512, 2) void moe_gemm1b(
    const float* __restrict__ x, const float* __restrict__ gate_w,
    const float* __restrict__ up_w, const int* __restrict__ wsI,
    unsigned short* __restrict__ h_ws) {
  int bid = blockIdx.x;
  int e = bid / (NT1f * MT_MAX);
  int r2 = bid % (NT1f * MT_MAX);
  int nt = r2 / MT_MAX, mt = r2 % MT_MAX;
  int cnt = wsI[e];
  int m0 = mt * BMf;
  if (m0 >= cnt) return;
  int n0 = nt * BNf;
  __shared__ short lA[BMf * LDKf];
  __shared__ short lG[BNf * LDKf];
  __shared__ short lU[BNf * LDKf];
  int tid = threadIdx.x, lane = tid & 63, wid = tid >> 6;
  int wm = wid >> 1, wn = wid & 1;
  int fr = lane & 15, fg = lane >> 4;
  int sr = tid >> 3, sc = (tid & 7) * 4;
  int tok[2];
#pragma unroll
  for (int p = 0; p < 2; ++p) {
    int r = p * 64 + sr;
    tok[p] = (m0 + r < cnt) ? wsI[64 + e * T_TOK + m0 + r] : -1;
  }
  const float* gw = gate_w + ((size_t)e * I_DIM + n0) * H_DIM;
  const float* uw = up_w + ((size_t)e * I_DIM + n0) * H_DIM;
  f32x4 accG[2][4] = {}, accU[2][4] = {};
  for (int k0 = 0; k0 < H_DIM; k0 += 32) {
    float4 va[2], vg[2], vu[2];
#pragma unroll
    for (int p = 0; p < 2; ++p) {
      int r = p * 64 + sr;
      va[p] = (tok[p] >= 0) ? *(const float4*)(x + (size_t)tok[p] * H_DIM + k0 + sc)
                            : make_float4(0.f, 0.f, 0.f, 0.f);
      vg[p] = *(const float4*)(gw + (size_t)r * H_DIM + k0 + sc);
      vu[p] = *(const float4*)(uw + (size_t)r * H_DIM + k0 + sc);
    }
#pragma unroll
    for (int p = 0; p < 2; ++p) {
      int r = p * 64 + sr;
      short4v a4 = {f2bf(va[p].x), f2bf(va[p].y), f2bf(va[p].z), f2bf(va[p].w)};
      short4v g4 = {f2bf(vg[p].x), f2bf(vg[p].y), f2bf(vg[p].z), f2bf(vg[p].w)};
      short4v u4 = {f2bf(vu[p].x), f2bf(vu[p].y), f2bf(vu[p].z), f2bf(vu[p].w)};
      *(short4v*)(lA + r * LDKf + sc) = a4;
      *(short4v*)(lG + r * LDKf + sc) = g4;
      *(short4v*)(lU + r * LDKf + sc) = u4;
    }
    __syncthreads();
    bf16x8 af[2], gf[4], uf[4];
#pragma unroll
    for (int m = 0; m < 2; ++m)
      af[m] = *(const bf16x8*)(lA + (wm * 32 + m * 16 + fr) * LDKf + fg * 8);
#pragma unroll
    for (int n = 0; n < 4; ++n) {
      gf[n] = *(const bf16x8*)(lG + (wn * 64 + n * 16 + fr) * LDKf + fg * 8);
      uf[n] = *(const bf16x8*)(lU + (wn * 64 + n * 16 + fr) * LDKf + fg * 8);
    }
#pragma unroll
    for (int m = 0; m < 2; ++m)
#pragma unroll
      for (int n = 0; n < 4; ++n) {
        accG[m][n] = __builtin_amdgcn_mfma_f32_16x16x32_bf16(af[m], gf[n], accG[m][n], 0, 0, 0);
        accU[m][n] = __builtin_amdgcn_mfma_f32_16x16x32_bf16(af[m], uf[n], accU[m][n], 0, 0, 0);
      }
    __syncthreads();
  }
#pragma unroll
  for (int m = 0; m < 2; ++m)
#pragma unroll
    for (int j = 0; j < 4; ++j) {
      int lr = wm * 32 + m * 16 + fg * 4 + j;
      int grow = m0 + lr;
      if (grow < cnt) {
        size_t rowbase = (size_t)(e * T_TOK + grow) * I_DIM + n0 + wn * 64;
#pragma unroll
        for (int n = 0; n < 4; ++n) {
          float g = accG[m][n][j], u = accU[m][n][j];
          h_ws[rowbase + n * 16 + fr] = (unsigned short)f2bf(g * u / (1.f + __expf(-g)));
        }
      }
    }
}

__global__ __launch_bounds__(256, 2) void moe_gemm2b(
    const unsigned short* __restrict__ h_ws, const float* __restrict__ down_w,
    const int* __restrict__ wsI, const float* __restrict__ routw,
    float* __restrict__ out) {
  int bid = blockIdx.x;
  int e = bid / (NT2f * MT_MAX);
  int r2 = bid % (NT2f * MT_MAX);
  int nt = r2 / MT_MAX, mt = r2 % MT_MAX;
  int cnt = wsI[e];
  int m0 = mt * BMf;
  if (m0 >= cnt) return;
  int n0 = nt * BNf;
  __shared__ short lA[BMf * LDKf];
  __shared__ short lB[BNf * LDKf];
  int tid = threadIdx.x, lane = tid & 63, wid = tid >> 6;
  int wm = wid >> 1, wn = wid & 1;
  int fr = lane & 15, fg = lane >> 4;
  int ar = tid >> 2, ac = (tid & 3) * 8;
  int br = tid >> 3, bc = (tid & 7) * 4;
  const float* dw = down_w + ((size_t)e * H_DIM + n0) * I_DIM;
  f32x4 acc[4][4] = {};
  for (int k0 = 0; k0 < I_DIM; k0 += 32) {
    bf16x8 va[2];
    float4 vb[4];
#pragma unroll
    for (int p = 0; p < 2; ++p) {
      int r = p * 64 + ar;
      bf16x8 v = {0, 0, 0, 0, 0, 0, 0, 0};
      if (m0 + r < cnt)
        v = *(const bf16x8*)(h_ws + (size_t)(e * T_TOK + m0 + r) * I_DIM + k0 + ac);
      va[p] = v;
    }
#pragma unroll
    for (int p = 0; p < 4; ++p)
      vb[p] = *(const float4*)(dw + (size_t)(p * 32 + br) * I_DIM + k0 + bc);
#pragma unroll
    for (int p = 0; p < 2; ++p)
      *(bf16x8*)(lA + (p * 64 + ar) * LDKf + ac) = va[p];
#pragma unroll
    for (int p = 0; p < 4; ++p) {
      short4v b4 = {f2bf(vb[p].x), f2bf(vb[p].y), f2bf(vb[p].z), f2bf(vb[p].w)};
      *(short4v*)(lB + (p * 32 + br) * LDKf + bc) = b4;
    }
    __syncthreads();
    bf16x8 af[4], bfr[4];
#pragma unroll
    for (int m = 0; m < 4; ++m)
      af[m] = *(const bf16x8*)(lA + (wm * 64 + m * 16 + fr) * LDKf + fg * 8);
#pragma unroll
    for (int n = 0; n < 4; ++n)
      bfr[n] = *(const bf16x8*)(lB + (wn * 64 + n * 16 + fr) * LDKf + fg * 8);
#pragma unroll
    for (int m = 0; m < 4; ++m)
#pragma unroll
      for (int n = 0; n < 4; ++n)
        acc[m][n] = __builtin_amdgcn_mfma_f32_16x16x32_bf16(af[m], bfr[n], acc[m][n], 0, 0, 0);
    __syncthreads();
  }
#pragma unroll
  for (int m = 0; m < 4; ++m)
#pragma unroll
    for (int j = 0; j < 4; ++j) {
      int lr = wm * 64 + m * 16 + fg * 4 + j;
      int grow = m0 + lr;
      if (grow < cnt) {
        int t = wsI[64 + e * T_TOK + grow];
        float w = routw[(size_t)t * NEXP + e];
        float* orow = out + (size_t)t * H_DIM + n0 + wn * 64;
#pragma unroll
        for (int n = 0; n < 4; ++n)
          atomicAdd(orow + n * 16 + fr, acc[m][n][j] * w);
      }
    }
}

extern "C" void kernel_launch(void* const* d_in, const int* in_sizes, int n_in,
                              void* d_out, int out_size, void* d_ws, size_t ws_size,
                              hipStream_t stream) {
  const float* x      = (const float*)d_in[0];
  const float* gate_w = (const float*)d_in[1];
  const float* up_w   = (const float*)d_in[2];
  const float* down_w = (const float*)d_in[3];
  const float* routw  = (const float*)d_in[4];
  float* out = (float*)d_out;
  int* wsI = (int*)d_ws;

  hipMemsetAsync(d_out, 0, (size_t)out_size * sizeof(float), stream);
  moe_compact<<<1, 512, 0, stream>>>(routw, wsI);

  if (ws_size >= WS_A_BYTES) {
    unsigned short* wbf = (unsigned short*)((char*)d_ws + 131072);
    unsigned short* xc  = (unsigned short*)((char*)d_ws + 37879808);
    unsigned short* h   = (unsigned short*)((char*)d_ws + 48365568);
    wconv<<<2304, 512, 0, stream>>>(gate_w, up_w, down_w, wbf);
    xgather<<<256, 256, 0, stream>>>(x, wsI, xc);
    moe_gemm1a<<<8 * 16 * 12, 512, 0, stream>>>(xc, wbf, wsI, h);
    moe_gemm2a<<<8 * 16 * 8, 512, 0, stream>>>(h, wbf, wsI, routw, out);
  } else {
    unsigned short* h_ws = (unsigned short*)((char*)d_ws + (1 << 17));
    moe_gemm1b<<<NEXP * NT1f * MT_MAX, 512, 0, stream>>>(x, gate_w, up_w, wsI, h_ws);
    moe_gemm2b<<<NEXP * NT2f * MT_MAX, 256, 0, stream>>>(h_ws, down_w, wsI, routw, out);
  }
}